// Round 3
// baseline (29326.141 us; speedup 1.0000x reference)
//
#include <hip/hip_runtime.h>
#include <math.h>

// ---------------------------------------------------------------------------
// Persistent-RNN LSTM v3 for MI355X — fence-free coherent h-state.
//   B=128, T=512, IN=64, H=1024, 2 layers, head OUT=1 on last step.
//
// Key changes vs v2 (which spent 85% of cycles stalled on agent fences):
//  - NO __threadfence / L2 invalidate. Cross-WG data (h-state, flags) uses
//    relaxed AGENT-scope atomics (sc1 -> served at MALL, L2 bypassed).
//    Read-only data (xT, weights, bi) uses normal loads -> stays L2-resident.
//  - Distributed flag barrier: flags[wg] = iter, wave 0 polls all 256.
//  - Decomposition: 128 col-groups x 2 batch-groups. WG owns 8 h-cols
//    (32 gate rows = 2 B-tiles) x 64 batch rows (4 A-tiles).
//    Zero-dup k-split over 8 waves; partial accs reduced via LDS ds_add_f32.
//    Cell update: 1 cell/thread/layer, no shuffles.
// ---------------------------------------------------------------------------

#define Hd 1024
#define Bd 128
#define Td 512
#define INd 64
#define NWG 256
#define NTHR 512

typedef _Float16 f16;
typedef _Float16 half8 __attribute__((ext_vector_type(8)));
typedef float f32x4 __attribute__((ext_vector_type(4)));

__device__ __forceinline__ half8 ld_h8_agent(const f16* p) {
    union { unsigned long long u[2]; half8 h; } v;
    v.u[0] = __hip_atomic_load((const unsigned long long*)p,
                               __ATOMIC_RELAXED, __HIP_MEMORY_SCOPE_AGENT);
    v.u[1] = __hip_atomic_load(((const unsigned long long*)p) + 1,
                               __ATOMIC_RELAXED, __HIP_MEMORY_SCOPE_AGENT);
    return v.h;
}
__device__ __forceinline__ void st_h_agent(f16* p, float x) {
    f16 hv = (f16)x;
    unsigned short u = __builtin_bit_cast(unsigned short, hv);
    __hip_atomic_store((unsigned short*)p, u,
                       __ATOMIC_RELAXED, __HIP_MEMORY_SCOPE_AGENT);
}

// ---------------- init: bi0/bi1, zero h buffers (both parities), flags ------
__global__ __launch_bounds__(512) void init_state(
    const float* __restrict__ bnd, const float* __restrict__ Wb0,
    const float* __restrict__ bb0, const float* __restrict__ Wb1,
    const float* __restrict__ bb1,
    float* __restrict__ bi0, float* __restrict__ bi1,
    f16* __restrict__ h0buf, f16* __restrict__ h1buf,
    unsigned int* __restrict__ flags)
{
    int idx = blockIdx.x * 512 + threadIdx.x;   // [0, B*H)
    int b = idx >> 10;
    int h = idx & 1023;
    float b0v = bnd[b * 2 + 0], b1v = bnd[b * 2 + 1];
    bi0[idx] = b0v * Wb0[h * 2 + 0] + b1v * Wb0[h * 2 + 1] + bb0[h];
    bi1[idx] = b0v * Wb1[h * 2 + 0] + b1v * Wb1[h * 2 + 1] + bb1[h];
    h0buf[idx] = (f16)0.f;  h0buf[idx + Bd * Hd] = (f16)0.f;
    h1buf[idx] = (f16)0.f;  h1buf[idx + Bd * Hd] = (f16)0.f;
    if (idx < NWG) flags[idx] = 0u;
}

// ---------------- transpose x [B,T,IN] f32 -> xT [T,B,IN] f16 ---------------
__global__ __launch_bounds__(512) void xpose(
    const float* __restrict__ x, f16* __restrict__ xT)
{
    int idx = blockIdx.x * 512 + threadIdx.x;   // [0, B*T*IN)
    int b = idx >> 15;           // T*IN = 32768
    int t = (idx >> 6) & 511;
    int i = idx & 63;
    xT[((size_t)t * Bd + b) * INd + i] = (f16)x[idx];
}

// ---------------- persistent LSTM ----------------
__global__ __launch_bounds__(NTHR, 2) void lstm_persist(
    const f16* __restrict__ xT,
    f16* __restrict__ h0b_, f16* __restrict__ h1b_,
    const float* __restrict__ bi0, const float* __restrict__ bi1,
    const float* __restrict__ Wx0, const float* __restrict__ bx0,
    const float* __restrict__ Uh0, const float* __restrict__ bh0,
    const float* __restrict__ Wx1, const float* __restrict__ bx1,
    const float* __restrict__ Uh1, const float* __restrict__ bh1,
    const float* __restrict__ fcW, const float* __restrict__ fcb,
    float* __restrict__ out, unsigned int* __restrict__ flags)
{
    const int tid  = threadIdx.x;
    const int w    = tid >> 6;        // wave 0..7
    const int lane = tid & 63;
    const int n    = lane & 15;       // MFMA col index
    const int q    = lane >> 4;       // quad 0..3
    const int wg   = blockIdx.x;
    const int cg   = wg & 127;        // col group  -> cols Cb..Cb+7
    const int bg   = wg >> 7;         // batch group-> rows Rb..Rb+63
    const int Cb   = cg * 8;
    const int Rb   = bg * 64;
    const size_t S2 = (size_t)Bd * Hd;

    __shared__ float ACC[2][8][256];   // [layer][tile a*2+bt][(q*4+r)*16+n] : 16 KB
    __shared__ float red[8];

    // B-fragment row j = bt*16+n -> gate (j>>3), col (j&7)
    int grow[2];
    #pragma unroll
    for (int bt = 0; bt < 2; ++bt) {
        int j = bt * 16 + n;
        grow[bt] = (j >> 3) * Hd + Cb + (j & 7);
    }

    // ---- L1 weights: wave w holds k-frags w*8..w*8+7 (w<4: Wx1/h0 half,
    //      w>=4: Uh1/h1 half), both B-tiles. 64 VGPRs. Zero duplication. ----
    half8 wL1[8][2];
    {
        const float* Wsrc = (w < 4) ? Wx1 : Uh1;
        const int kbase = (w < 4 ? w : w - 4) * 256;
        #pragma unroll
        for (int kk = 0; kk < 8; ++kk) {
            #pragma unroll
            for (int bt = 0; bt < 2; ++bt) {
                const float* rp = Wsrc + (size_t)grow[bt] * Hd + kbase + kk * 32 + q * 8;
                half8 hv;
                #pragma unroll
                for (int j = 0; j < 8; ++j) hv[j] = (f16)rp[j];
                wL1[kk][bt] = hv;
            }
        }
    }
    // ---- L0 weights: waves 0-3 hold Uh0 k-frags w*8..w*8+7; waves 6,7 hold
    //      the x-projection frag (Wx0 cols (w-6)*32..+31). ----
    half8 wL0[8][2];
    half8 wX[2];
    if (w < 4) {
        #pragma unroll
        for (int kk = 0; kk < 8; ++kk) {
            #pragma unroll
            for (int bt = 0; bt < 2; ++bt) {
                const float* rp = Uh0 + (size_t)grow[bt] * Hd + w * 256 + kk * 32 + q * 8;
                half8 hv;
                #pragma unroll
                for (int j = 0; j < 8; ++j) hv[j] = (f16)rp[j];
                wL0[kk][bt] = hv;
            }
        }
    } else if (w >= 6) {
        #pragma unroll
        for (int bt = 0; bt < 2; ++bt) {
            const float* rp = Wx0 + (size_t)grow[bt] * INd + (w - 6) * 32 + q * 8;
            half8 hv;
            #pragma unroll
            for (int j = 0; j < 8; ++j) hv[j] = (f16)rp[j];
            wX[bt] = hv;
        }
    }

    // ---- per-thread cell state: cell (row=Rb+tid>>3, col=Cb+tid&7) ----
    const int crow = tid >> 3, ccol = tid & 7;
    const int gR = Rb + crow, gC = Cb + ccol;
    float gb0[4], gb1[4];
    #pragma unroll
    for (int g = 0; g < 4; ++g) {
        gb0[g] = bx0[g * Hd + gC] + bh0[g * Hd + gC];
        gb1[g] = bx1[g * Hd + gC] + bh1[g * Hd + gC];
    }
    const float ba0 = bi0[(size_t)gR * Hd + gC];
    const float ba1 = bi1[(size_t)gR * Hd + gC];
    float c0s = 0.f, c1s = 0.f;
    const int ca = crow >> 4, crr = crow & 15;

    // ---- main sequence: iter s computes layer1(s) and layer0(s+1) ----
    for (int s = -1; s <= 511; ++s) {
        const bool doL0 = (s < 511), doL1 = (s >= 0);
        const f16* h0r = h0b_ + (size_t)(s & 1) * S2;         // h0(s)
        f16*       h0w = h0b_ + (size_t)((s + 1) & 1) * S2;   // h0(s+1)
        const f16* h1r = h1b_ + (size_t)((s - 1) & 1) * S2;   // h1(s-1)
        f16*       h1w = h1b_ + (size_t)(s & 1) * S2;         // h1(s)

        // zero ACC (separated from prior cell reads by the barrier syncs)
        {
            float* az = &ACC[0][0][0];
            #pragma unroll
            for (int i = 0; i < 8; ++i) az[tid + i * 512] = 0.f;
        }

        f32x4 aL1[4][2], aL0[4][2];
        #pragma unroll
        for (int a = 0; a < 4; ++a)
            #pragma unroll
            for (int bt = 0; bt < 2; ++bt) {
                aL1[a][bt] = (f32x4){0.f, 0.f, 0.f, 0.f};
                aL0[a][bt] = (f32x4){0.f, 0.f, 0.f, 0.f};
            }

        if (w < 4) {
            // A = h0(s) rows Rb+a*16+n, cols w*256+kk*32+q*8 (coherent);
            // feeds BOTH layer1(s) k-half0 and layer0(s+1) h-part.
            #pragma unroll
            for (int kk = 0; kk < 8; ++kk) {
                half8 Af[4];
                #pragma unroll
                for (int a = 0; a < 4; ++a)
                    Af[a] = ld_h8_agent(h0r + (size_t)(Rb + a * 16 + n) * Hd
                                        + w * 256 + kk * 32 + q * 8);
                if (doL1) {
                    #pragma unroll
                    for (int a = 0; a < 4; ++a)
                        #pragma unroll
                        for (int bt = 0; bt < 2; ++bt)
                            aL1[a][bt] = __builtin_amdgcn_mfma_f32_16x16x32_f16(
                                Af[a], wL1[kk][bt], aL1[a][bt], 0, 0, 0);
                }
                if (doL0) {
                    #pragma unroll
                    for (int a = 0; a < 4; ++a)
                        #pragma unroll
                        for (int bt = 0; bt < 2; ++bt)
                            aL0[a][bt] = __builtin_amdgcn_mfma_f32_16x16x32_f16(
                                Af[a], wL0[kk][bt], aL0[a][bt], 0, 0, 0);
                }
            }
        } else {
            if (doL1) {
                // A = h1(s-1), cols (w-4)*256+kk*32+q*8 (coherent)
                #pragma unroll
                for (int kk = 0; kk < 8; ++kk) {
                    half8 Af[4];
                    #pragma unroll
                    for (int a = 0; a < 4; ++a)
                        Af[a] = ld_h8_agent(h1r + (size_t)(Rb + a * 16 + n) * Hd
                                            + (w - 4) * 256 + kk * 32 + q * 8);
                    #pragma unroll
                    for (int a = 0; a < 4; ++a)
                        #pragma unroll
                        for (int bt = 0; bt < 2; ++bt)
                            aL1[a][bt] = __builtin_amdgcn_mfma_f32_16x16x32_f16(
                                Af[a], wL1[kk][bt], aL1[a][bt], 0, 0, 0);
                }
            }
            if (w >= 6 && doL0) {
                // x-projection: A = xT[s+1] (normal cached loads, read-only)
                const f16* xb = xT + (size_t)(s + 1) * Bd * INd;
                #pragma unroll
                for (int a = 0; a < 4; ++a) {
                    half8 Af = *(const half8*)(xb + (size_t)(Rb + a * 16 + n) * INd
                                               + (w - 6) * 32 + q * 8);
                    #pragma unroll
                    for (int bt = 0; bt < 2; ++bt)
                        aL0[a][bt] = __builtin_amdgcn_mfma_f32_16x16x32_f16(
                            Af, wX[bt], aL0[a][bt], 0, 0, 0);
                }
            }
        }

        __syncthreads();   // ACC zero + all partials ready

        // ---- k-reduction via LDS float atomics ----
        if (doL1) {
            #pragma unroll
            for (int a = 0; a < 4; ++a)
                #pragma unroll
                for (int bt = 0; bt < 2; ++bt)
                    #pragma unroll
                    for (int r = 0; r < 4; ++r)
                        atomicAdd(&ACC[1][a * 2 + bt][(q * 4 + r) * 16 + n],
                                  aL1[a][bt][r]);
        }
        if (doL0 && (w < 4 || w >= 6)) {
            #pragma unroll
            for (int a = 0; a < 4; ++a)
                #pragma unroll
                for (int bt = 0; bt < 2; ++bt)
                    #pragma unroll
                    for (int r = 0; r < 4; ++r)
                        atomicAdd(&ACC[0][a * 2 + bt][(q * 4 + r) * 16 + n],
                                  aL0[a][bt][r]);
        }
        __syncthreads();

        // ---- cell updates: gates (i,f) in B-tile 0 at n=col / 8+col,
        //      (o,g) in B-tile 1. One cell per thread per layer. ----
        if (doL0) {
            float ip = ACC[0][ca * 2 + 0][crr * 16 + ccol]     + gb0[0];
            float fp = ACC[0][ca * 2 + 0][crr * 16 + 8 + ccol] + gb0[1] + ba0;
            float op = ACC[0][ca * 2 + 1][crr * 16 + ccol]     + gb0[2];
            float gp = ACC[0][ca * 2 + 1][crr * 16 + 8 + ccol] + gb0[3];
            float I = 1.f / (1.f + expf(-ip));
            float F = 1.f / (1.f + expf(-fp));
            float O = 1.f / (1.f + expf(-op));
            float G = tanhf(gp);
            c0s = F * c0s + I * G;
            st_h_agent(&h0w[(size_t)gR * Hd + gC], O * tanhf(c0s));
        }
        if (doL1) {
            float ip = ACC[1][ca * 2 + 0][crr * 16 + ccol]     + gb1[0];
            float fp = ACC[1][ca * 2 + 0][crr * 16 + 8 + ccol] + gb1[1] + ba1;
            float op = ACC[1][ca * 2 + 1][crr * 16 + ccol]     + gb1[2];
            float gp = ACC[1][ca * 2 + 1][crr * 16 + 8 + ccol] + gb1[3];
            float I = 1.f / (1.f + expf(-ip));
            float F = 1.f / (1.f + expf(-fp));
            float O = 1.f / (1.f + expf(-op));
            float G = tanhf(gp);
            c1s = F * c1s + I * G;
            st_h_agent(&h1w[(size_t)gR * Hd + gC], O * tanhf(c1s));
        }

        // ---- fence-free grid barrier: per-WG flag + full poll ----
        asm volatile("s_waitcnt vmcnt(0)" ::: "memory");  // my wave's h-stores at MALL
        __syncthreads();                                  // all waves drained
        const unsigned target = (unsigned)(s + 2);
        if (tid == 0)
            __hip_atomic_store(&flags[wg], target,
                               __ATOMIC_RELAXED, __HIP_MEMORY_SCOPE_AGENT);
        if (w == 0) {
            while (true) {
                unsigned f0 = __hip_atomic_load(&flags[lane],
                                 __ATOMIC_RELAXED, __HIP_MEMORY_SCOPE_AGENT);
                unsigned f1 = __hip_atomic_load(&flags[64 + lane],
                                 __ATOMIC_RELAXED, __HIP_MEMORY_SCOPE_AGENT);
                unsigned f2 = __hip_atomic_load(&flags[128 + lane],
                                 __ATOMIC_RELAXED, __HIP_MEMORY_SCOPE_AGENT);
                unsigned f3 = __hip_atomic_load(&flags[192 + lane],
                                 __ATOMIC_RELAXED, __HIP_MEMORY_SCOPE_AGENT);
                bool ok = (f0 >= target) && (f1 >= target) &&
                          (f2 >= target) && (f3 >= target);
                if (__all(ok)) break;
                __builtin_amdgcn_s_sleep(2);
            }
        }
        asm volatile("" ::: "memory");   // keep next-iter loads below the poll
        __syncthreads();
    }

    // ---- fc head: out[b] = fcW . h1(511)[b] + fcb (h1 slot 1) ----
    if (wg < Bd) {
        float partial = 0.f;
        if (tid < 256) {
            const f16* hrow = h1b_ + S2 + (size_t)wg * Hd + tid * 4;
            union { unsigned long long u; f16 h[4]; } v;
            v.u = __hip_atomic_load((const unsigned long long*)hrow,
                                    __ATOMIC_RELAXED, __HIP_MEMORY_SCOPE_AGENT);
            const float* fw = fcW + tid * 4;
            partial = (float)v.h[0] * fw[0] + (float)v.h[1] * fw[1]
                    + (float)v.h[2] * fw[2] + (float)v.h[3] * fw[3];
        }
        #pragma unroll
        for (int off = 32; off > 0; off >>= 1) partial += __shfl_down(partial, off);
        if (lane == 0) red[w] = partial;
        __syncthreads();
        if (tid == 0) {
            float t = 0.f;
            #pragma unroll
            for (int i = 0; i < 8; ++i) t += red[i];
            out[wg] = t + fcb[0];
        }
    }
}

// ---------------------------------------------------------------------------
extern "C" void kernel_launch(void* const* d_in, const int* in_sizes, int n_in,
                              void* d_out, int out_size, void* d_ws, size_t ws_size,
                              hipStream_t stream) {
    const float* x        = (const float*)d_in[0];
    const float* boundary = (const float*)d_in[1];
    const float* Wx0      = (const float*)d_in[2];
    const float* bx0      = (const float*)d_in[3];
    const float* Uh0      = (const float*)d_in[4];
    const float* bh0      = (const float*)d_in[5];
    const float* Wb0      = (const float*)d_in[6];
    const float* bb0      = (const float*)d_in[7];
    const float* Wx1      = (const float*)d_in[8];
    const float* bx1      = (const float*)d_in[9];
    const float* Uh1      = (const float*)d_in[10];
    const float* bh1      = (const float*)d_in[11];
    const float* Wb1      = (const float*)d_in[12];
    const float* bb1      = (const float*)d_in[13];
    const float* fcW      = (const float*)d_in[14];
    const float* fcb      = (const float*)d_in[15];
    float* out = (float*)d_out;

    // workspace layout (bytes)
    char* ws = (char*)d_ws;
    f16*   xT    = (f16*)(ws);                       // 8,388,608
    f16*   h0buf = (f16*)(ws + 8388608);             //   524,288 (2 parities)
    f16*   h1buf = (f16*)(ws + 8912896);             //   524,288
    float* bi0   = (float*)(ws + 9437184);           //   524,288
    float* bi1   = (float*)(ws + 9961472);           //   524,288
    unsigned int* flags = (unsigned int*)(ws + 10485760);  // 1 KB

    init_state<<<256, 512, 0, stream>>>(boundary, Wb0, bb0, Wb1, bb1,
                                        bi0, bi1, h0buf, h1buf, flags);
    xpose<<<8192, 512, 0, stream>>>(x, xT);

    void* args[] = {
        (void*)&xT, (void*)&h0buf, (void*)&h1buf, (void*)&bi0, (void*)&bi1,
        (void*)&Wx0, (void*)&bx0, (void*)&Uh0, (void*)&bh0,
        (void*)&Wx1, (void*)&bx1, (void*)&Uh1, (void*)&bh1,
        (void*)&fcW, (void*)&fcb, (void*)&out, (void*)&flags
    };
    hipLaunchCooperativeKernel((void*)lstm_persist, dim3(NWG), dim3(NTHR),
                               args, 0, stream);
}